// Round 8
// baseline (98.334 us; speedup 1.0000x reference)
//
#include <hip/hip_runtime.h>

// Inverse 2-level orthonormal Haar DWT with zero details ==
// 4x4 nearest-neighbor upsample scaled by 1/4.
// in : [B=128, C=3, 128, 128] f32 (flat)   ( 25 MB)
// out: [B=128, C=3, 512, 512] f32 (flat)   (403 MB, 25,165,824 float4)
//
// R8: mimic the 6.9 TB/s fillBufferAligned structure — few persistent
// blocks, grid-stride float4 writes, plain stores. 512 blocks x 256 thr:
// the 131072-thread cohort writes a contiguous 2 MB window per iteration
// that slides monotonically through the output (HBM row locality), vs
// 24576 short-lived blocks spreading ~25-100 MB of in-flight addresses.
// Per-thread the decomposition is loop-invariant: stride 131072 float4s
// => w4 const, h const (1024 mod 512 == 0), bc += 2 per iter. Inner loop
// is load -> mul -> store with constant address strides; input working
// set per iteration is a sliding 128 KB (two channel-images) -> L2 serves
// the 4x re-reads, HBM fetch = 25 MB once.

typedef float f32x4 __attribute__((ext_vector_type(4)));

__global__ void __launch_bounds__(256) haar_upsample4_kernel(
        const float* __restrict__ z, float* __restrict__ out, int total4) {
    const int nthreads = gridDim.x * blockDim.x;          // 131072
    const int tid = blockIdx.x * blockDim.x + threadIdx.x;

    const int w4    = tid & 127;         // input float4-column, const
    const int rest0 = tid >> 7;
    const int h     = rest0 & 511;       // output row, const across iters
    const int h_in  = h >> 2;
    const int bc0   = rest0 >> 9;        // 0 or 1; advances by 2 per iter
    const int zoff  = (h_in << 7) + w4;  // const part of input index

    f32x4* o4 = reinterpret_cast<f32x4*>(out) + tid;
    const int iters = total4 / nthreads; // 192 (exact)

    #pragma unroll 4
    for (int it = 0; it < iters; ++it) {
        const float v = z[((bc0 + (it << 1)) << 14) + zoff] * 0.25f;
        const f32x4 o = {v, v, v, v};
        o4[(size_t)it * nthreads] = o;   // plain store, 1 KB/wave contiguous
    }
}

extern "C" void kernel_launch(void* const* d_in, const int* in_sizes, int n_in,
                              void* d_out, int out_size, void* d_ws, size_t ws_size,
                              hipStream_t stream) {
    const float* z = (const float*)d_in[0];
    float* out = (float*)d_out;
    const int total4 = out_size >> 2;    // 25,165,824
    haar_upsample4_kernel<<<512, 256, 0, stream>>>(z, out, total4);
}

// Round 9
// 87.168 us; speedup vs baseline: 1.1281x; 1.1281x over previous
//
#include <hip/hip_runtime.h>

// Inverse 2-level orthonormal Haar DWT with zero details ==
// 4x4 nearest-neighbor upsample scaled by 1/4.
// in : [B=128, C=3, 128, 128] f32 (flat)   ( 25 MB)
// out: [B=128, C=3, 512, 512] f32 (flat)   (403 MB, 25,165,824 float4)
//
// Structure = R3 (best pure kernel): 2048 blocks x 256 thr, grid-stride,
// one output float4 per thread per iter; the 524288-thread cohort writes an
// 8 MB contiguous window sliding monotonically (full-occupancy MLP; R8
// showed low-concurrency persistent blocks starve the store stream).
// Store policy hybrid (R6 A/B insight, now in ONE dispatch):
//  - iters 0..43 (371 MB): non-temporal — fastest steady-state stream
//    (write-combined straight toward HBM, no L2 LRU churn; R5=75.2 vs R7=82.8).
//  - iters 44..47 (last 32 MB = L2 capacity): plain stores — tail lines stay
//    dirty in L2 past kernel retire (timing doesn't wait for write-back) and
//    are overwritten in-place as write hits on the next replay.

typedef float f32x4 __attribute__((ext_vector_type(4)));

__global__ void __launch_bounds__(256) haar_upsample4_kernel(
        const float* __restrict__ z, float* __restrict__ out) {
    const int tid = blockIdx.x * 256 + threadIdx.x;   // 0 .. 524287
    f32x4* o4 = reinterpret_cast<f32x4*>(out);

    // i = tid + it*524288 ; decode i -> (bc, h_in, w4)
    #pragma unroll 4
    for (int it = 0; it < 44; ++it) {                 // nt body: 371 MB
        const int i    = tid + (it << 19);
        const int w4   = i & 127;
        const int rest = i >> 7;
        const int h    = rest & 511;
        const int bc   = rest >> 9;
        const int h_in = h >> 2;
        const float v  = z[(bc << 14) + (h_in << 7) + w4] * 0.25f;
        const f32x4 o  = {v, v, v, v};
        __builtin_nontemporal_store(o, o4 + i);
    }
    #pragma unroll
    for (int it = 44; it < 48; ++it) {                // plain tail: 32 MB
        const int i    = tid + (it << 19);
        const int w4   = i & 127;
        const int rest = i >> 7;
        const int h    = rest & 511;
        const int bc   = rest >> 9;
        const int h_in = h >> 2;
        const float v  = z[(bc << 14) + (h_in << 7) + w4] * 0.25f;
        const f32x4 o  = {v, v, v, v};
        o4[i] = o;
    }
}

extern "C" void kernel_launch(void* const* d_in, const int* in_sizes, int n_in,
                              void* d_out, int out_size, void* d_ws, size_t ws_size,
                              hipStream_t stream) {
    const float* z = (const float*)d_in[0];
    float* out = (float*)d_out;
    // total4 = out_size/4 = 25,165,824 = 48 iterations x 524,288 threads (exact)
    haar_upsample4_kernel<<<2048, 256, 0, stream>>>(z, out);
}